// Round 1
// baseline (1127.557 us; speedup 1.0000x reference)
//
#include <hip/hip_runtime.h>
#include <hip/hip_fp16.h>

typedef _Float16 half8 __attribute__((ext_vector_type(8)));
typedef _Float16 half4 __attribute__((ext_vector_type(4)));
typedef float floatx4 __attribute__((ext_vector_type(4)));

#define TT 512
#define EE 100
#define NBATCH 16
#define NBLK 64
#define WS_NEED ((size_t)NBLK * TT * 2048 * sizeof(_Float16))

typedef const __attribute__((address_space(1))) void gvoid_t;
typedef __attribute__((address_space(3))) void lvoid_t;

#define MFMA16 __builtin_amdgcn_mfma_f32_16x16x32_f16

__device__ __forceinline__ float sigm(float x) {
    return __builtin_amdgcn_rcpf(1.0f + __expf(-x));
}
__device__ __forceinline__ float tanh_(float x) {
    return __builtin_amdgcn_rcpf(1.0f + __expf(-2.0f * x)) * 2.0f - 1.0f;
}
__device__ __forceinline__ half4 cvt4(float4 v) {
    half4 h; h[0] = (_Float16)v.x; h[1] = (_Float16)v.y; h[2] = (_Float16)v.z; h[3] = (_Float16)v.w;
    return h;
}

// ---- pre-pass: X (fp32 [B][T][100]) -> fragment-ordered fp16 in d_ws ----
// Layout: xw[blk][t][c][m][8] halfs, c=k/8 (k padded to 128; k==100 is the
// bias-one column pairing with the bias column folded into W1ih fragments).
extern "C" __global__ void __launch_bounds__(256)
xfrag_prep(const float* __restrict__ X, _Float16* __restrict__ xw)
{
    const int bt  = blockIdx.x;            // blk*512 + t
    const int blk = bt >> 9;
    const int t   = bt & (TT - 1);
    const int tid = threadIdx.x;
    const int c   = tid >> 4, m = tid & 15;
    const int k0  = 8 * c;
    half8 v;
#pragma unroll
    for (int j = 0; j < 8; ++j) v[j] = (_Float16)0.0f;
    const float* p = X + ((size_t)(blk * 16 + m) * TT + t) * EE + k0;
    if (k0 + 8 <= EE) {                    // c <= 11: full 8 floats
        float4 lo = *(const float4*)p;
        float4 hi = *(const float4*)(p + 4);
        v[0] = (_Float16)lo.x; v[1] = (_Float16)lo.y; v[2] = (_Float16)lo.z; v[3] = (_Float16)lo.w;
        v[4] = (_Float16)hi.x; v[5] = (_Float16)hi.y; v[6] = (_Float16)hi.z; v[7] = (_Float16)hi.w;
    } else if (k0 < EE) {                  // c == 12: k=96..99 + bias at k=100
        float4 lo = *(const float4*)p;
        v[0] = (_Float16)lo.x; v[1] = (_Float16)lo.y; v[2] = (_Float16)lo.z; v[3] = (_Float16)lo.w;
        v[4] = (_Float16)1.0f;
    }
    *(half8*)&xw[(size_t)bt * 2048 + c * 128 + m * 8] = v;
}

// ---- main: 64 blocks x 512 threads (8 waves), block = 16 batches, all T ----
// SINGLE barrier per step.
// Region 1 (critical): L1 h-part MFMAs (acc pre-seeded with a1x) + cell update.
// Region 2 (shadow):  x(t+2) staging (global_load_lds -> xb), L2 gates
//   (gate-interleaved tiles: lane holds all 4 gates of one unit -> lane-local
//   cell update, no cross-wave handoff), a1x(t+1) = W1ih * x(t+1).
template<int USE_WS>
__global__ void __launch_bounds__(512, 1)
lstm_mfma4(const float* __restrict__ X, const _Float16* __restrict__ xw,
           const float* __restrict__ W1ih, const float* __restrict__ W1hh,
           const float* __restrict__ b1i,  const float* __restrict__ b1h,
           const float* __restrict__ W2ih, const float* __restrict__ W2hh,
           const float* __restrict__ b2i,  const float* __restrict__ b2h,
           const float* __restrict__ fc1w, const float* __restrict__ fc1b,
           const float* __restrict__ fc2w, const float* __restrict__ fc2b,
           float* __restrict__ out)
{
    const int tid  = threadIdx.x;
    const int w    = tid >> 6;
    const int lane = tid & 63;
    const int q    = lane >> 4;
    const int m    = lane & 15;
    const int b0   = blockIdx.x * NBATCH;

    __shared__ __align__(16) _Float16 h1b[2][4][4][16][8];   // 8 KB
    __shared__ __align__(16) _Float16 h2b[2][2][4][16][8];   // 4 KB
    __shared__ __align__(16) _Float16 xb [2][4][4][16][8];   // 8 KB (x frags, dbuf)
    __shared__ float fca[NBATCH][32];

    _Float16* const h1f = &h1b[0][0][0][0][0];
    _Float16* const h2f = &h2b[0][0][0][0][0];
    _Float16* const xbf = &xb [0][0][0][0][0];

    // zero recurrent state (+ xb pad/bias-one columns in fallback)
    for (int i = tid; i < 2 * 2048; i += 512) h1f[i] = (_Float16)0.0f;
    for (int i = tid; i < 2 * 1024; i += 512) h2f[i] = (_Float16)0.0f;
    if (!USE_WS) {
        for (int i = tid; i < 2 * 2048; i += 512) {
            const int k = i & 2047;     // bias-one at s=3,q=0,j=4 (k==100 col)
            xbf[i] = (k >= 1536 && k < 1664 && (k & 7) == 4) ? (_Float16)1.0f
                                                             : (_Float16)0.0f;
        }
    }

    // ---- weight fragments ----
    half8 w1ihf[4][4], w1hhf[4][4], w2ihf[2][4], w2hhf[2][2];
    floatx4 bias2v[2];
#pragma unroll
    for (int g = 0; g < 4; ++g) {
        const int r = g * 128 + 16 * w + m;
        const float bias = b1i[r] + b1h[r];
#pragma unroll
        for (int s = 0; s < 4; ++s) {
            half8 f;
#pragma unroll
            for (int j = 0; j < 8; ++j) {
                const int k = 32 * s + 8 * q + j;
                float v = 0.0f;
                if (k < EE) v = W1ih[r * EE + k];
                else if (k == EE) v = bias;          // pairs with x bias-one column
                f[j] = (_Float16)v;
            }
            w1ihf[g][s] = f;
        }
#pragma unroll
        for (int s = 0; s < 4; ++s) {
            half8 f;
#pragma unroll
            for (int j = 0; j < 8; ++j) f[j] = (_Float16)W1hh[r * 128 + 32 * s + 8 * q + j];
            w1hhf[g][s] = f;
        }
    }
    // L2, gate-interleaved rows: tile-local row rl -> gate (rl&3), unit 8w+4tau+(rl>>2).
    // A-fragment local row is m; C/D row is 4q+reg -> lane (q,m) ends up with
    // gates reg=0..3 of unit u = 8w+4tau+q for batch m.
#pragma unroll
    for (int tau = 0; tau < 2; ++tau) {
        const int rr = (m & 3) * 64 + 8 * w + 4 * tau + (m >> 2);   // W2 row for local row m
#pragma unroll
        for (int s = 0; s < 4; ++s) {
            half8 f;
#pragma unroll
            for (int j = 0; j < 8; ++j) f[j] = (_Float16)W2ih[rr * 128 + 32 * s + 8 * q + j];
            w2ihf[tau][s] = f;
        }
#pragma unroll
        for (int s = 0; s < 2; ++s) {
            half8 f;
#pragma unroll
            for (int j = 0; j < 8; ++j) f[j] = (_Float16)W2hh[rr * 64 + 32 * s + 8 * q + j];
            w2hhf[tau][s] = f;
        }
        const int uu = 8 * w + 4 * tau + q;
#pragma unroll
        for (int reg = 0; reg < 4; ++reg)
            bias2v[tau][reg] = b2i[reg * 64 + uu] + b2h[reg * 64 + uu];
    }

    const _Float16* xwb = xw + (size_t)blockIdx.x * TT * 2048;
    const int foff = q * 128 + m * 8;

    // fallback staging setup (x via regs -> LDS, 2-step-deep pipeline)
    int gaddr = 0, laddr = 0;
    bool xval = false;
    float4 xr = {0.f, 0.f, 0.f, 0.f};
    if (!USE_WS) {
        xval = tid < 400;
        const int f = xval ? tid : 0;
        const int n = f / 25, pp = f - 25 * n, e0 = 4 * pp;
        gaddr = (b0 + n) * (TT * EE) + e0;
        const int s = e0 >> 5, qr = (e0 >> 3) & 3, j0 = e0 & 7;
        laddr = ((s * 4 + qr) * 16 + n) * 8 + j0;
    }

    __syncthreads();   // zero-init visible before staging

    if (USE_WS) {
        if (w < 4) {   // stage x(0) -> xb[0], x(1) -> xb[1]; 1 KB per wave each
            __builtin_amdgcn_global_load_lds((gvoid_t*)(xwb + 0 * 2048 + w * 512 + lane * 8),
                                             (lvoid_t*)(xbf + 0 * 2048 + w * 512), 16, 0, 0);
            __builtin_amdgcn_global_load_lds((gvoid_t*)(xwb + 1 * 2048 + w * 512 + lane * 8),
                                             (lvoid_t*)(xbf + 1 * 2048 + w * 512), 16, 0, 0);
        }
    } else if (xval) {
        *(half4*)&xbf[0 * 2048 + laddr] = cvt4(*(const float4*)&X[gaddr + 0 * EE]);
        *(half4*)&xbf[1 * 2048 + laddr] = cvt4(*(const float4*)&X[gaddr + 1 * EE]);
        xr = *(const float4*)&X[gaddr + 2 * EE];          // x(2) held in regs
    }
    __syncthreads();   // staging visible (drains global_load_lds)

    // ---- warmup: a1x(0) = W1ih * x(0) (bias folded via ones column) ----
    floatx4 a1x[4];
#pragma unroll
    for (int g = 0; g < 4; ++g) a1x[g] = (floatx4){0.f, 0.f, 0.f, 0.f};
    {
        const _Float16* xc = xbf + 0 * 2048 + foff;
#pragma unroll
        for (int s = 0; s < 4; ++s) {
            half8 bx = *(const half8*)(xc + s * 512);
#pragma unroll
            for (int g = 0; g < 4; ++g) a1x[g] = MFMA16(w1ihf[g][s], bx, a1x[g], 0, 0, 0);
        }
    }

    floatx4 c1 = {0.f, 0.f, 0.f, 0.f};
    float c2[2] = {0.f, 0.f};
    const int vv = 2 * w + (q >> 1);   // h1 fragment slot
    const int jj = 4 * (q & 1);

#pragma unroll 1
    for (int t = 0; t < TT; ++t) {
        const int cur = t & 1, nxt = cur ^ 1;

        // ---- region 1 (critical path): L1 h-part, acc seeded with a1x ----
        {
            const _Float16* hp = h1f + nxt * 2048 + foff;
#pragma unroll
            for (int s = 0; s < 4; ++s) {
                half8 bh = *(const half8*)(hp + s * 512);
#pragma unroll
                for (int g = 0; g < 4; ++g)
                    a1x[g] = MFMA16(w1hhf[g][s], bh, a1x[g], 0, 0, 0);
            }
        }
        {   // L1 cell update (in-register)
            half4 hv;
#pragma unroll
            for (int r = 0; r < 4; ++r) {
                const float iv = sigm(a1x[0][r]);
                const float fv = sigm(a1x[1][r]);
                const float gv = tanh_(a1x[2][r]);
                const float ov = sigm(a1x[3][r]);
                const float c  = fv * c1[r] + iv * gv;
                c1[r] = c;
                hv[r] = (_Float16)(ov * tanh_(c));
            }
            *(half4*)&h1b[cur][vv >> 2][vv & 3][m][jj] = hv;
        }
        __syncthreads();   // the ONLY barrier per step

        // ---- region 2 (shadow): staging, L2, next-step a1x ----
        if (USE_WS) {
            if (w < 4) {   // issue x(t+2) -> xb[cur]; drained at next barrier
                const int tn = (t + 2 < TT) ? (t + 2) : (TT - 1);
                __builtin_amdgcn_global_load_lds((gvoid_t*)(xwb + (size_t)tn * 2048 + w * 512 + lane * 8),
                                                 (lvoid_t*)(xbf + cur * 2048 + w * 512), 16, 0, 0);
            }
        } else if (xval) {
            *(half4*)&xbf[cur * 2048 + laddr] = cvt4(xr);   // x(t+2) -> xb[(t+2)&1]
            const int tn = (t + 3 < TT) ? (t + 3) : (TT - 1);
            xr = *(const float4*)&X[gaddr + tn * EE];
        }

        // L2 gates: 2 gate-interleaved tiles per wave
        floatx4 a2[2] = { bias2v[0], bias2v[1] };
        {
            const _Float16* hc = h1f + cur * 2048 + foff;
#pragma unroll
            for (int s = 0; s < 4; ++s) {
                half8 bh = *(const half8*)(hc + s * 512);
                a2[0] = MFMA16(w2ihf[0][s], bh, a2[0], 0, 0, 0);
                a2[1] = MFMA16(w2ihf[1][s], bh, a2[1], 0, 0, 0);
            }
            const _Float16* h2p = h2f + nxt * 1024 + foff;
#pragma unroll
            for (int s = 0; s < 2; ++s) {
                half8 b2v = *(const half8*)(h2p + s * 512);
                a2[0] = MFMA16(w2hhf[0][s], b2v, a2[0], 0, 0, 0);
                a2[1] = MFMA16(w2hhf[1][s], b2v, a2[1], 0, 0, 0);
            }
        }

        // a1x(t+1) = W1ih * x(t+1)   (off critical path)
        {
            const _Float16* xc = xbf + nxt * 2048 + foff;
#pragma unroll
            for (int g = 0; g < 4; ++g) a1x[g] = (floatx4){0.f, 0.f, 0.f, 0.f};
#pragma unroll
            for (int s = 0; s < 4; ++s) {
                half8 bx = *(const half8*)(xc + s * 512);
#pragma unroll
                for (int g = 0; g < 4; ++g)
                    a1x[g] = MFMA16(w1ihf[g][s], bx, a1x[g], 0, 0, 0);
            }
        }

        // L2 cell update: fully lane-local (lane holds all 4 gates of unit u)
#pragma unroll
        for (int tau = 0; tau < 2; ++tau) {
            const float iv = sigm(a2[tau][0]);
            const float fv = sigm(a2[tau][1]);
            const float gv = tanh_(a2[tau][2]);
            const float ov = sigm(a2[tau][3]);
            const float c  = fv * c2[tau] + iv * gv;
            c2[tau] = c;
            const int u = 8 * w + 4 * tau + q;
            h2f[cur * 1024 + (u >> 5) * 512 + ((u >> 3) & 3) * 128 + m * 8 + (u & 7)]
                = (_Float16)(ov * tanh_(c));
        }
        // next iteration's barrier orders h2(t) before its phase-B reads
    }
    __syncthreads();

    // ---- FC head (h2 final in h2b[1]) ----
    {
        const int nb = tid >> 5, o = tid & 31;   // 512 = 16 x 32 exactly
        float s = fc1b[o];
#pragma unroll
        for (int k = 0; k < 64; ++k)
            s += fc1w[o * 64 + k] * (float)h2b[1][k >> 5][(k >> 3) & 3][nb][k & 7];
        fca[nb][o] = fmaxf(s, 0.0f);
    }
    __syncthreads();
    if (tid < NBATCH) {
        float s = fc2b[0];
#pragma unroll
        for (int k = 0; k < 32; ++k) s += fc2w[k] * fca[tid][k];
        out[b0 + tid] = sigm(s);
    }
}

extern "C" void kernel_launch(void* const* d_in, const int* in_sizes, int n_in,
                              void* d_out, int out_size, void* d_ws, size_t ws_size,
                              hipStream_t stream) {
    const float* X    = (const float*)d_in[0];
    const float* W1ih = (const float*)d_in[1];
    const float* W1hh = (const float*)d_in[2];
    const float* b1i  = (const float*)d_in[3];
    const float* b1h  = (const float*)d_in[4];
    const float* W2ih = (const float*)d_in[5];
    const float* W2hh = (const float*)d_in[6];
    const float* b2i  = (const float*)d_in[7];
    const float* b2h  = (const float*)d_in[8];
    const float* fc1w = (const float*)d_in[9];
    const float* fc1b = (const float*)d_in[10];
    const float* fc2w = (const float*)d_in[11];
    const float* fc2b = (const float*)d_in[12];
    _Float16* xw = (_Float16*)d_ws;

    if (ws_size >= WS_NEED) {
        hipLaunchKernelGGL(xfrag_prep, dim3(NBLK * TT), dim3(256), 0, stream, X, xw);
        hipLaunchKernelGGL(lstm_mfma4<1>, dim3(NBLK), dim3(512), 0, stream,
                           X, xw, W1ih, W1hh, b1i, b1h, W2ih, W2hh, b2i, b2h,
                           fc1w, fc1b, fc2w, fc2b, (float*)d_out);
    } else {
        hipLaunchKernelGGL(lstm_mfma4<0>, dim3(NBLK), dim3(512), 0, stream,
                           X, xw, W1ih, W1hh, b1i, b1h, W2ih, W2hh, b2i, b2h,
                           fc1w, fc1b, fc2w, fc2b, (float*)d_out);
    }
}